// Round 15
// baseline (119.597 us; speedup 1.0000x reference)
//
#include <hip/hip_runtime.h>

#define BB 4
#define CC 256
#define CQ 32
#define NN 4096   // 64*64

typedef __attribute__((ext_vector_type(8))) short bf16x8;
typedef __attribute__((ext_vector_type(4))) float f32x4;

__device__ __forceinline__ unsigned short f2bf(float f) {
    unsigned int u = __float_as_uint(f);
    unsigned int r = (u + 0x7fffu + ((u >> 16) & 1u)) >> 16;
    return (unsigned short)r;
}

// ---------------------------------------------------------------------------
// K1: Q/K projections -> transposed bf16 buffers [b][n][cq].  (R13-identical)
// grid (NN/128, 8, BB), block 128: grp 0-3 = Q rows grp*8..+8,
// grp 4-7 = K rows (grp-4)*8..+8. grp 0 also streams out = x.
// ---------------------------------------------------------------------------
__global__ __launch_bounds__(128) void qk_proj_kernel(
    const float* __restrict__ x,
    const float* __restrict__ wq, const float* __restrict__ bq,
    const float* __restrict__ wk, const float* __restrict__ bk,
    unsigned short* __restrict__ Qtb, unsigned short* __restrict__ Ktb,
    float* __restrict__ out)
{
    const int n   = blockIdx.x * 128 + threadIdx.x;
    const int grp = blockIdx.y;
    const int b   = blockIdx.z;
    const bool isQ = (grp < 4);
    const bool doCopy = (grp == 0);
    const int o0 = (grp & 3) * 8;

    const float* w    = isQ ? wq : wk;
    const float* bias = isQ ? bq : bk;

    float acc[8];
    #pragma unroll
    for (int u = 0; u < 8; ++u) acc[u] = bias[o0 + u];

    const float* xp = x + (size_t)b * CC * NN + n;
    float* op = out + (size_t)b * CC * NN + n;
    const float* wp = w + (size_t)o0 * CC;
    #pragma unroll 8
    for (int c = 0; c < CC; ++c) {
        float xv = xp[(size_t)c * NN];
        if (doCopy) op[(size_t)c * NN] = xv;
        #pragma unroll
        for (int u = 0; u < 8; ++u) acc[u] += wp[u * CC + c] * xv;
    }

    unsigned int pk[4];
    #pragma unroll
    for (int j = 0; j < 4; ++j)
        pk[j] = (unsigned int)f2bf(acc[2 * j]) | ((unsigned int)f2bf(acc[2 * j + 1]) << 16);

    unsigned short* dst = (isQ ? Qtb : Ktb) + ((size_t)b * NN + n) * CQ;
    *reinterpret_cast<uint4*>(dst + o0) = make_uint4(pk[0], pk[1], pk[2], pk[3]);
}

// ---------------------------------------------------------------------------
// K2: V projection -> Vt[b][n][c]  (gamma-guarded; grid-stride, small grid)
// ---------------------------------------------------------------------------
__global__ __launch_bounds__(256) void v_proj_kernel(
    const float* __restrict__ x,
    const float* __restrict__ wv, const float* __restrict__ bv,
    const float* __restrict__ gamma,
    float* __restrict__ Vt)
{
    if (gamma[0] == 0.f) return;
    for (int task = blockIdx.x; task < 2048; task += 512) {
        const int n  = (task & 15) * 256 + threadIdx.x;
        const int c0 = ((task >> 4) & 31) * 8;
        const int b  = task >> 9;

        float acc[8];
        #pragma unroll
        for (int u = 0; u < 8; ++u) acc[u] = 0.f;

        const float* xp = x + (size_t)b * CC * NN + n;
        #pragma unroll 4
        for (int c = 0; c < CC; ++c) {
            float xv = xp[(size_t)c * NN];
            #pragma unroll
            for (int u = 0; u < 8; ++u) acc[u] += wv[(size_t)(c0 + u) * CC + c] * xv;
        }
        #pragma unroll
        for (int u = 0; u < 8; ++u)
            Vt[((size_t)b * NN + n) * CC + c0 + u] = acc[u] + bv[c0 + u];
    }
}

// ---------------------------------------------------------------------------
// K3: SINGLE-pass MFMA energy + softmax, E cached in regs as packed bf16.
// Block = 16 q-rows x 4096 cols, 8 waves; wave w owns cols [w*512, +512).
// mfma_f32_16x16x32_bf16 swapped (A=K,B=Q): lane(l15,g) holds
// E[i0+l15][w*512+t*16+g*4+r], r=0..3 -> q-row is LANE-LOCAL & SCALAR.
// Per tile: 1 MFMA -> 4 exp (f32) -> row-sum += -> pack bf16 (trunc) into
// cache[64] (static idx). Reduce: 2 shfl_xor + 16-val cross-wave merge.
// Store: unpack, *is, float4 direct (4 consecutive cols/lane; successive t
// chain sequentially -> L2 line-merge). No 2nd pass, no LDS transpose.
// No max-subtract (energies O(few); fp32 exp safe; softmax shift-invariant).
// ---------------------------------------------------------------------------
__global__ __launch_bounds__(512) void attn_kernel(
    const unsigned short* __restrict__ Qtb,
    const unsigned short* __restrict__ Ktb,
    float* __restrict__ att)
{
    __shared__ float red_s[8][16];
    __shared__ float rowis[16];

    const int tid  = threadIdx.x;
    const int w    = tid >> 6;
    const int lane = tid & 63;
    const int l15  = lane & 15;
    const int g    = lane >> 4;   // 0..3
    const int b    = blockIdx.y;
    const int i0   = blockIdx.x * 16;

    // Q-frag (B operand): Q[i0+l15][g*8 .. g*8+7]
    const bf16x8 qf = *reinterpret_cast<const bf16x8*>(
        Qtb + ((size_t)b * NN + i0 + l15) * CQ + g * 8);

    // K-frag base (A operand): K[w*512 + t*16 + l15][g*8 .. +7]
    const unsigned short* kfb = Ktb + ((size_t)b * NN + w * 512 + l15) * CQ + g * 8;

    unsigned int cache[64];
    float s = 0.f;

    {
        bf16x8 kn = *reinterpret_cast<const bf16x8*>(kfb);
        #pragma unroll
        for (int t = 0; t < 32; ++t) {
            bf16x8 kf = kn;
            if (t < 31)
                kn = *reinterpret_cast<const bf16x8*>(kfb + (size_t)(t + 1) * 16 * CQ);
            f32x4 acc{};
            acc = __builtin_amdgcn_mfma_f32_16x16x32_bf16(kf, qf, acc, 0, 0, 0);
            float e0 = __expf(acc[0]);
            float e1 = __expf(acc[1]);
            float e2 = __expf(acc[2]);
            float e3 = __expf(acc[3]);
            s += (e0 + e1) + (e2 + e3);
            // pack bf16 by truncation (rel err <= 2^-8; values O(1))
            cache[2 * t]     = (__float_as_uint(e0) >> 16) | (__float_as_uint(e1) & 0xffff0000u);
            cache[2 * t + 1] = (__float_as_uint(e2) >> 16) | (__float_as_uint(e3) & 0xffff0000u);
        }
    }

    // row-sum: reduce over g (lanes sharing l15) then across waves
    s += __shfl_xor(s, 16, 64);
    s += __shfl_xor(s, 32, 64);
    if (lane < 16) red_s[w][l15] = s;
    __syncthreads();
    if (tid < 16) {
        float t2 = red_s[0][tid];
        #pragma unroll
        for (int ww = 1; ww < 8; ++ww) t2 += red_s[ww][tid];
        rowis[tid] = 1.0f / t2;
    }
    __syncthreads();
    const float is = rowis[l15];

    // store: lane -> row i0+l15, cols w*512 + t*16 + g*4 .. +3 (float4)
    float* ab = att + ((size_t)b * NN + i0 + l15) * NN + w * 512 + g * 4;
    #pragma unroll
    for (int t = 0; t < 32; ++t) {
        const unsigned int lo = cache[2 * t];
        const unsigned int hi = cache[2 * t + 1];
        float4 v;
        v.x = __uint_as_float(lo << 16) * is;
        v.y = __uint_as_float(lo & 0xffff0000u) * is;
        v.z = __uint_as_float(hi << 16) * is;
        v.w = __uint_as_float(hi & 0xffff0000u) * is;
        *reinterpret_cast<float4*>(ab + t * 16) = v;
    }
}

// ---------------------------------------------------------------------------
// K4: PV (gamma-guarded; grid-stride, small grid)
// ---------------------------------------------------------------------------
__global__ __launch_bounds__(256) void pv_kernel(
    const float* __restrict__ att, const float* __restrict__ Vt,
    const float* __restrict__ gamma, float* __restrict__ Pt)
{
    if (gamma[0] == 0.f) return;
    const size_t total = (size_t)BB * NN * CC;
    for (size_t idx = (size_t)blockIdx.x * 256 + threadIdx.x; idx < total;
         idx += (size_t)2048 * 256) {
        const int c = (int)(idx % CC);
        const size_t bn = idx / CC;
        const int i = (int)(bn % NN);
        const int b = (int)(bn / NN);

        const float* arow = att + ((size_t)b * NN + i) * NN;
        const float* vcol = Vt + (size_t)b * NN * CC + c;
        float acc = 0.f;
        for (int j = 0; j < NN; ++j) acc += arow[j] * vcol[(size_t)j * CC];
        Pt[idx] = acc;
    }
}

// ---------------------------------------------------------------------------
// K5: out = gamma * PV + x (gamma!=0 only; grid-stride, small grid)
// ---------------------------------------------------------------------------
__global__ __launch_bounds__(256) void out_kernel(
    const float* __restrict__ x, const float* __restrict__ Pt,
    const float* __restrict__ gamma, float* __restrict__ out)
{
    const float g = gamma[0];
    if (g == 0.f) return;
    const size_t total4 = (size_t)BB * CC * NN / 4;
    for (size_t t = (size_t)blockIdx.x * 256 + threadIdx.x; t < total4;
         t += (size_t)1024 * 256) {
        const size_t i4 = t * 4;
        float4 v = *reinterpret_cast<const float4*>(x + i4);
        #pragma unroll
        for (int e = 0; e < 4; ++e) {
            const size_t idx = i4 + e;
            const int n = (int)(idx % NN);
            const size_t bc = idx / NN;
            const int c = (int)(bc % CC);
            const int bb = (int)(bc / CC);
            (&v.x)[e] += g * Pt[((size_t)bb * NN + n) * CC + c];
        }
        *reinterpret_cast<float4*>(out + i4) = v;
    }
}

extern "C" void kernel_launch(void* const* d_in, const int* in_sizes, int n_in,
                              void* d_out, int out_size, void* d_ws, size_t ws_size,
                              hipStream_t stream)
{
    const float* x     = (const float*)d_in[0];
    const float* wq    = (const float*)d_in[1];
    const float* bq    = (const float*)d_in[2];
    const float* wk    = (const float*)d_in[3];
    const float* bk    = (const float*)d_in[4];
    const float* wv    = (const float*)d_in[5];
    const float* bv    = (const float*)d_in[6];
    const float* gamma = (const float*)d_in[7];

    float* out = (float*)d_out;                    // [B,C,W,H]
    float* att = out + (size_t)BB * CC * NN;       // [B,N,N]

    unsigned short* Qtb = (unsigned short*)d_ws;             // B*N*CQ bf16 (1 MB)
    unsigned short* Ktb = Qtb + (size_t)BB * NN * CQ;        // 1 MB
    float* Vt = (float*)(Ktb + (size_t)BB * NN * CQ);        // B*N*C f32
    float* Pt = Vt + (size_t)BB * NN * CC;

    qk_proj_kernel<<<dim3(NN / 128, 8, BB), 128, 0, stream>>>(x, wq, bq, wk, bk, Qtb, Ktb, out);
    v_proj_kernel<<<dim3(512), 256, 0, stream>>>(x, wv, bv, gamma, Vt);
    attn_kernel<<<dim3(NN / 16, BB), 512, 0, stream>>>(Qtb, Ktb, att);
    pv_kernel<<<dim3(2048), 256, 0, stream>>>(att, Vt, gamma, Pt);
    out_kernel<<<dim3(1024), 256, 0, stream>>>(x, Pt, gamma, out);
}

// Round 16
// 104.348 us; speedup vs baseline: 1.1461x; 1.1461x over previous
//
#include <hip/hip_runtime.h>

#define BB 4
#define CC 256
#define CQ 32
#define NN 4096   // 64*64

typedef __attribute__((ext_vector_type(8))) short bf16x8;
typedef __attribute__((ext_vector_type(16))) float f32x16;

__device__ __forceinline__ unsigned short f2bf(float f) {
    unsigned int u = __float_as_uint(f);
    unsigned int r = (u + 0x7fffu + ((u >> 16) & 1u)) >> 16;
    return (unsigned short)r;
}

// ---------------------------------------------------------------------------
// K1: Q/K projections -> transposed bf16 buffers [b][n][cq].  (R14-identical)
// grid (NN/128, 8, BB), block 128: grp 0-3 = Q rows grp*8..+8,
// grp 4-7 = K rows (grp-4)*8..+8. grp 0 also streams out = x.
// ---------------------------------------------------------------------------
__global__ __launch_bounds__(128) void qk_proj_kernel(
    const float* __restrict__ x,
    const float* __restrict__ wq, const float* __restrict__ bq,
    const float* __restrict__ wk, const float* __restrict__ bk,
    unsigned short* __restrict__ Qtb, unsigned short* __restrict__ Ktb,
    float* __restrict__ out)
{
    const int n   = blockIdx.x * 128 + threadIdx.x;
    const int grp = blockIdx.y;
    const int b   = blockIdx.z;
    const bool isQ = (grp < 4);
    const bool doCopy = (grp == 0);
    const int o0 = (grp & 3) * 8;

    const float* w    = isQ ? wq : wk;
    const float* bias = isQ ? bq : bk;

    float acc[8];
    #pragma unroll
    for (int u = 0; u < 8; ++u) acc[u] = bias[o0 + u];

    const float* xp = x + (size_t)b * CC * NN + n;
    float* op = out + (size_t)b * CC * NN + n;
    const float* wp = w + (size_t)o0 * CC;
    #pragma unroll 8
    for (int c = 0; c < CC; ++c) {
        float xv = xp[(size_t)c * NN];
        if (doCopy) op[(size_t)c * NN] = xv;
        #pragma unroll
        for (int u = 0; u < 8; ++u) acc[u] += wp[u * CC + c] * xv;
    }

    unsigned int pk[4];
    #pragma unroll
    for (int j = 0; j < 4; ++j)
        pk[j] = (unsigned int)f2bf(acc[2 * j]) | ((unsigned int)f2bf(acc[2 * j + 1]) << 16);

    unsigned short* dst = (isQ ? Qtb : Ktb) + ((size_t)b * NN + n) * CQ;
    *reinterpret_cast<uint4*>(dst + o0) = make_uint4(pk[0], pk[1], pk[2], pk[3]);
}

// ---------------------------------------------------------------------------
// K2: V projection -> Vt[b][n][c]  (gamma-guarded; grid-stride, small grid)
// ---------------------------------------------------------------------------
__global__ __launch_bounds__(256) void v_proj_kernel(
    const float* __restrict__ x,
    const float* __restrict__ wv, const float* __restrict__ bv,
    const float* __restrict__ gamma,
    float* __restrict__ Vt)
{
    if (gamma[0] == 0.f) return;
    for (int task = blockIdx.x; task < 2048; task += 256) {
        const int n  = (task & 15) * 256 + threadIdx.x;
        const int c0 = ((task >> 4) & 31) * 8;
        const int b  = task >> 9;

        float acc[8];
        #pragma unroll
        for (int u = 0; u < 8; ++u) acc[u] = 0.f;

        const float* xp = x + (size_t)b * CC * NN + n;
        #pragma unroll 4
        for (int c = 0; c < CC; ++c) {
            float xv = xp[(size_t)c * NN];
            #pragma unroll
            for (int u = 0; u < 8; ++u) acc[u] += wv[(size_t)(c0 + u) * CC + c] * xv;
        }
        #pragma unroll
        for (int u = 0; u < 8; ++u)
            Vt[((size_t)b * NN + n) * CC + c0 + u] = acc[u] + bv[c0 + u];
    }
}

// ---------------------------------------------------------------------------
// K3: 2-pass MFMA energy + softmax (R14 math, bit-identical). ONLY change:
// XCD-aware bijective block swizzle — flat grid 512, orig = (flat>>3) +
// (flat&7)*64, so each XCD owns a CONTIGUOUS 64-tile (32 MB) output chunk:
// L2 write-back per XCD becomes long sequential streams (DRAM page locality)
// instead of 8 XCDs interleaving 128B touches over the whole 256 MB output.
// Single-buffered transpose tile tr[8][32][33] (33.8 KB).
// ---------------------------------------------------------------------------
__global__ __launch_bounds__(512, 4) void attn_kernel(
    const unsigned short* __restrict__ Qtb,
    const unsigned short* __restrict__ Ktb,
    float* __restrict__ att)
{
    __shared__ float red_s[8][32];
    __shared__ float rowls[32];
    __shared__ float tr[8][32][33];

    const int tid  = threadIdx.x;
    const int w    = tid >> 6;
    const int lane = tid & 63;
    const int l31  = lane & 31;
    const int h    = lane >> 5;

    // XCD-aware bijective swizzle: 512 blocks, XCD (flat&7) gets orig chunk
    // [ (flat&7)*64, +64 ) — contiguous row-tiles, mostly one batch.
    const int flat = blockIdx.x;
    const int orig = (flat >> 3) + ((flat & 7) << 6);
    const int b    = orig >> 7;
    const int i0   = (orig & 127) * 32;

    // Q-frags (B operand): col i = i0+l31; k-chunks h and h+2 (8 cq each)
    const unsigned short* qb = Qtb + ((size_t)b * NN + i0 + l31) * CQ;
    const bf16x8 a0 = *reinterpret_cast<const bf16x8*>(qb + h * 8);
    const bf16x8 a1 = *reinterpret_cast<const bf16x8*>(qb + (h + 2) * 8);

    // K-frags (A operand): row j = w*512 + u*32 + l31; same k-chunks
    const unsigned short* kf = Ktb + ((size_t)b * NN + w * 512 + l31) * CQ;

    // ---------------- pass 1: per-lane row-sum of exp (prefetched) ---------
    float s = 0.f;
    {
        bf16x8 nb0 = *reinterpret_cast<const bf16x8*>(kf + h * 8);
        bf16x8 nb1 = *reinterpret_cast<const bf16x8*>(kf + (h + 2) * 8);
        #pragma unroll
        for (int u = 0; u < 16; ++u) {
            bf16x8 b0 = nb0, b1 = nb1;
            if (u < 15) {
                const unsigned short* kp = kf + (size_t)(u + 1) * 32 * CQ;
                nb0 = *reinterpret_cast<const bf16x8*>(kp + h * 8);
                nb1 = *reinterpret_cast<const bf16x8*>(kp + (h + 2) * 8);
            }
            f32x16 acc{};
            acc = __builtin_amdgcn_mfma_f32_32x32x16_bf16(b0, a0, acc, 0, 0, 0);
            acc = __builtin_amdgcn_mfma_f32_32x32x16_bf16(b1, a1, acc, 0, 0, 0);
            float p0 = 0.f, p1 = 0.f;
            #pragma unroll
            for (int q = 0; q < 16; q += 2) {
                p0 += __expf(acc[q]);
                p1 += __expf(acc[q + 1]);
            }
            s += p0 + p1;
        }
    }
    s += __shfl_xor(s, 32, 64);
    if (h == 0) red_s[w][l31] = s;
    __syncthreads();
    if (tid < 32) {
        float t = red_s[0][tid];
        #pragma unroll
        for (int ww = 1; ww < 8; ++ww) t += red_s[ww][tid];
        rowls[tid] = -__logf(t);
    }
    __syncthreads();
    const float lis = rowls[l31];

    // ------- pass 2: recompute (prefetched), LDS transpose, store ----------
    float* abase = att + ((size_t)b * NN + i0) * NN + w * 512;
    {
        bf16x8 nb0 = *reinterpret_cast<const bf16x8*>(kf + h * 8);
        bf16x8 nb1 = *reinterpret_cast<const bf16x8*>(kf + (h + 2) * 8);
        #pragma unroll
        for (int u = 0; u < 16; ++u) {
            bf16x8 b0 = nb0, b1 = nb1;
            if (u < 15) {
                const unsigned short* kp = kf + (size_t)(u + 1) * 32 * CQ;
                nb0 = *reinterpret_cast<const bf16x8*>(kp + h * 8);
                nb1 = *reinterpret_cast<const bf16x8*>(kp + (h + 2) * 8);
            }
            f32x16 acc{};
            acc = __builtin_amdgcn_mfma_f32_32x32x16_bf16(b0, a0, acc, 0, 0, 0);
            acc = __builtin_amdgcn_mfma_f32_32x32x16_bf16(b1, a1, acc, 0, 0, 0);
            // write transposed: lane holds query-row l31, k-col (q&3)+8*(q>>2)+4h
            #pragma unroll
            for (int q = 0; q < 16; ++q) {
                const int kc = (q & 3) + 8 * (q >> 2) + 4 * h;
                tr[w][kc][l31] = __expf(acc[q] + lis);
            }
            // read back row-major: lane -> (row 2k+h, col l31); half-wave = line
            #pragma unroll
            for (int k = 0; k < 16; ++k) {
                const int row = 2 * k + h;
                abase[(size_t)row * NN + u * 32 + l31] = tr[w][l31][row];
            }
        }
    }
}

// ---------------------------------------------------------------------------
// K4: PV (gamma-guarded; grid-stride, small grid)
// ---------------------------------------------------------------------------
__global__ __launch_bounds__(256) void pv_kernel(
    const float* __restrict__ att, const float* __restrict__ Vt,
    const float* __restrict__ gamma, float* __restrict__ Pt)
{
    if (gamma[0] == 0.f) return;
    const size_t total = (size_t)BB * NN * CC;
    for (size_t idx = (size_t)blockIdx.x * 256 + threadIdx.x; idx < total;
         idx += (size_t)1024 * 256) {
        const int c = (int)(idx % CC);
        const size_t bn = idx / CC;
        const int i = (int)(bn % NN);
        const int b = (int)(bn / NN);

        const float* arow = att + ((size_t)b * NN + i) * NN;
        const float* vcol = Vt + (size_t)b * NN * CC + c;
        float acc = 0.f;
        for (int j = 0; j < NN; ++j) acc += arow[j] * vcol[(size_t)j * CC];
        Pt[idx] = acc;
    }
}

// ---------------------------------------------------------------------------
// K5: out = gamma * PV + x (gamma!=0 only; grid-stride, small grid)
// ---------------------------------------------------------------------------
__global__ __launch_bounds__(256) void out_kernel(
    const float* __restrict__ x, const float* __restrict__ Pt,
    const float* __restrict__ gamma, float* __restrict__ out)
{
    const float g = gamma[0];
    if (g == 0.f) return;
    const size_t total4 = (size_t)BB * CC * NN / 4;
    for (size_t t = (size_t)blockIdx.x * 256 + threadIdx.x; t < total4;
         t += (size_t)512 * 256) {
        const size_t i4 = t * 4;
        float4 v = *reinterpret_cast<const float4*>(x + i4);
        #pragma unroll
        for (int e = 0; e < 4; ++e) {
            const size_t idx = i4 + e;
            const int n = (int)(idx % NN);
            const size_t bc = idx / NN;
            const int c = (int)(bc % CC);
            const int bb = (int)(bc / CC);
            (&v.x)[e] += g * Pt[((size_t)bb * NN + n) * CC + c];
        }
        *reinterpret_cast<float4*>(out + i4) = v;
    }
}

extern "C" void kernel_launch(void* const* d_in, const int* in_sizes, int n_in,
                              void* d_out, int out_size, void* d_ws, size_t ws_size,
                              hipStream_t stream)
{
    const float* x     = (const float*)d_in[0];
    const float* wq    = (const float*)d_in[1];
    const float* bq    = (const float*)d_in[2];
    const float* wk    = (const float*)d_in[3];
    const float* bk    = (const float*)d_in[4];
    const float* wv    = (const float*)d_in[5];
    const float* bv    = (const float*)d_in[6];
    const float* gamma = (const float*)d_in[7];

    float* out = (float*)d_out;                    // [B,C,W,H]
    float* att = out + (size_t)BB * CC * NN;       // [B,N,N]

    unsigned short* Qtb = (unsigned short*)d_ws;             // B*N*CQ bf16 (1 MB)
    unsigned short* Ktb = Qtb + (size_t)BB * NN * CQ;        // 1 MB
    float* Vt = (float*)(Ktb + (size_t)BB * NN * CQ);        // B*N*C f32
    float* Pt = Vt + (size_t)BB * NN * CC;

    qk_proj_kernel<<<dim3(NN / 128, 8, BB), 128, 0, stream>>>(x, wq, bq, wk, bk, Qtb, Ktb, out);
    v_proj_kernel<<<dim3(256), 256, 0, stream>>>(x, wv, bv, gamma, Vt);
    attn_kernel<<<dim3(512), 512, 0, stream>>>(Qtb, Ktb, att);
    pv_kernel<<<dim3(1024), 256, 0, stream>>>(att, Vt, gamma, Pt);
    out_kernel<<<dim3(512), 256, 0, stream>>>(x, Pt, gamma, out);
}